// Round 6
// baseline (213.846 us; speedup 1.0000x reference)
//
#include <hip/hip_runtime.h>
#include <hip/hip_bf16.h>

typedef __attribute__((ext_vector_type(8))) __bf16 bf16x8;
typedef __attribute__((ext_vector_type(4))) float f32x4;

#define S_TOK 4096
#define NB 2
#define NH 16
#define DH 128
#define DEG 4
#define SSP 1024
#define QB 64
#define KB 64
#define TOKS 4096 /* floats per token row */
#define SCALE 0.08838834764831845f

#define KROWB 256                 /* Kb bytes per sparse token row */
#define VROWB 2048                /* Vb bytes per d row (1024 s * 2B) */
#define KTILE (KB * KROWB)        /* 16 KB */
#define VTILE (64 * 128)          /* 8 KB: 64 d-rows x 128 B */
#define BUFSZ (KTILE + VTILE)     /* 24576 */
#define KB_BYTES (32L * 1024 * 256)  /* 8 MB */

union U8 {
  bf16x8 v;
  unsigned u[4];
  unsigned short s[8];
};

__device__ __forceinline__ unsigned short f2bfu(float x) {
  __bf16 b = (__bf16)x;  // RNE; pairs into v_cvt_pk_bf16_f32
  return __builtin_bit_cast(unsigned short, b);
}
__device__ __forceinline__ unsigned pkbf(float lo, float hi) {
  return (unsigned)f2bfu(lo) | ((unsigned)f2bfu(hi) << 16);
}
__device__ __forceinline__ void gload16(const void* g, void* l) {
  __builtin_amdgcn_global_load_lds(
      (const __attribute__((address_space(1))) unsigned*)g,
      (__attribute__((address_space(3))) unsigned*)l, 16, 0, 0);
}

// ---- pass 1: sparse-gather + bf16 convert into LDS-ready swizzled layouts ----
// Kb[bh][s][256B], 16B-chunk col ^= (s&7)<<4.   Vb[bh][d][2048B], col ^= (d&7)<<4
// (XOR applied within each 128B s-tile window).
__global__ __launch_bounds__(256) void mlsa_conv(
    const float* __restrict__ Kg, const float* __restrict__ Vg,
    unsigned char* __restrict__ Kb, unsigned char* __restrict__ Vb) {
  __shared__ __align__(16) unsigned char sm[64 * 144];
  const int tid = (int)threadIdx.x;
  const int bid = (int)blockIdx.x;
  if (bid < 2048) {  // K path
    int gid = bid * 256 + tid;
    int row = gid >> 4;  // bh*1024 + s
    int chunk = gid & 15;
    int bh = row >> 10, s = row & 1023;
    int b = bh >> 4, h = bh & 15;
    long src = (long)(s * DEG + (h & 3)) * TOKS + b * (NH * DH) + h * DH + chunk * 8;
    f32x4 x0 = *(const f32x4*)(Kg + src);
    f32x4 x1 = *(const f32x4*)(Kg + src + 4);
    uint4 w;
    w.x = pkbf(x0[0], x0[1]);
    w.y = pkbf(x0[2], x0[3]);
    w.z = pkbf(x1[0], x1[1]);
    w.w = pkbf(x1[2], x1[3]);
    int col = (chunk * 16) ^ ((s & 7) << 4);
    *(uint4*)(Kb + (long)row * KROWB + col) = w;
  } else {  // V path: transpose 64s x 64d tile via LDS
    int vb = bid - 2048;
    int bh = vb >> 5, st = (vb >> 1) & 15, dt = vb & 1;
    int b = bh >> 4, h = bh & 15;
    const int sl = (tid & 31) * 2;  // local s pair
    const int dl = (tid >> 5) * 8;  // local d chunk
    long base = (long)((st * 64 + sl) * DEG + (h & 3)) * TOKS + b * (NH * DH) +
                h * DH + dt * 64 + dl;
    f32x4 a0 = *(const f32x4*)(Vg + base);
    f32x4 a1 = *(const f32x4*)(Vg + base + 4);
    f32x4 b0 = *(const f32x4*)(Vg + base + 4 * TOKS);
    f32x4 b1 = *(const f32x4*)(Vg + base + 4 * TOKS + 4);
    #pragma unroll
    for (int i = 0; i < 4; ++i)
      *(unsigned*)(sm + (dl + i) * 144 + sl * 2) = pkbf(a0[i], b0[i]);
    #pragma unroll
    for (int i = 0; i < 4; ++i)
      *(unsigned*)(sm + (dl + 4 + i) * 144 + sl * 2) = pkbf(a1[i], b1[i]);
    __syncthreads();
    #pragma unroll
    for (int rep = 0; rep < 2; ++rep) {
      int id = tid + rep * 256;
      int row = id >> 3, sc = id & 7;  // row = local d
      uint4 w = *(const uint4*)(sm + row * 144 + sc * 16);
      int colg = st * 128 + ((sc * 16) ^ ((row & 7) << 4));
      *(uint4*)(Vb + ((long)bh * 128 + dt * 64 + row) * VROWB + colg) = w;
    }
  }
}

// ---- pass 2: fused causal attention + scatter ----
__global__ __launch_bounds__(256, 2) void mlsa_attn(
    const float* __restrict__ Qg, const unsigned char* __restrict__ Kb,
    const unsigned char* __restrict__ Vb, float* __restrict__ Og,
    float* __restrict__ Dg) {
  __shared__ __align__(16) unsigned char lds[2 * BUFSZ];

  const int bid = (int)blockIdx.x;
  const int bh = bid & 31;
  const int j = (bid >> 5) & 7;  // pair id: tiles {j, 15-j} -> 17 steps/block
  const int dhv = bid >> 8;      // d-half
  const int b = bh >> 4;
  const int h = bh & 15;
  const int hm4 = h & 3;
  const int tid = (int)threadIdx.x;
  const int wv = tid >> 6;
  const int ln = tid & 63;
  const int g = ln >> 4;
  const int c = ln & 15;
  const size_t bhoff = (size_t)b * (NH * DH) + (size_t)h * DH;
  const int dbase = dhv * 64;
  const long kbase = (long)bh * (1024L * KROWB);
  const long vbase = (long)bh * (128L * VROWB);

  auto stage = [&](int buf, int kt) {
    unsigned char* KL = lds + buf * BUFSZ;
    unsigned char* VL = KL + KTILE;
    #pragma unroll
    for (int p = 0; p < 4; ++p) {
      int off = wv * 4096 + p * 1024;  // wave-uniform LDS base; lane*16 implicit
      gload16(Kb + kbase + (long)kt * KTILE + off + ln * 16, KL + off);
    }
    #pragma unroll
    for (int p = 0; p < 2; ++p) {
      int off = wv * 2048 + p * 1024;
      int o2 = off + ln * 16;
      int row = o2 >> 7, colb = o2 & 127;
      gload16(Vb + vbase + (long)(dbase + row) * VROWB + kt * 128 + colb,
              VL + off);
    }
  };

  int cur = 0;

  for (int ph = 0; ph < 2; ++ph) {
    const int qt = ph ? (15 - j) : j;
    const int qbase = qt * QB + wv * 16;
    const int q_sp = qbase + c;

    if (ph == 0) stage(0, 0);  // DMA flies under zero-fill + Q load/convert

    // ---- Q loads (fp32) ----
    f32x4 qraw[8];
    {
      const float* qrow = Qg + (size_t)(q_sp * DEG + hm4) * TOKS + bhoff + g * 8;
      #pragma unroll
      for (int dc = 0; dc < 4; ++dc) {
        qraw[2 * dc] = *(const f32x4*)(qrow + dc * 32);
        qraw[2 * dc + 1] = *(const f32x4*)(qrow + dc * 32 + 4);
      }
    }

    if (ph == 0) {
      // zero-fill the 3 non-selected token offsets, both tiles, this d-half
      const f32x4 z = {0.f, 0.f, 0.f, 0.f};
      for (int u = 0; u < 24; ++u) {
        int fid = u * 256 + tid;
        int col = fid & 15;
        int row = fid >> 4;  // 0..383
        int t2 = row >= 192;
        int r2 = row - (t2 ? 192 : 0);
        int rr = r2 >> 6;
        int qi = (t2 ? (15 - j) : j) * QB + (r2 & 63);
        int off = (hm4 + 1 + rr) & 3;
        *(f32x4*)(Og + (size_t)(qi * DEG + off) * TOKS + bhoff + dbase + col * 4) = z;
      }
    }

    // ---- convert Q (pre-scaled), B-operand layout ----
    bf16x8 qf[4];
    #pragma unroll
    for (int dc = 0; dc < 4; ++dc) {
      U8 t;
      #pragma unroll
      for (int i = 0; i < 4; ++i) {
        t.s[i] = f2bfu(qraw[2 * dc][i] * SCALE);
        t.s[4 + i] = f2bfu(qraw[2 * dc + 1][i] * SCALE);
      }
      qf[dc] = t.v;
    }

    if (ph == 0) __syncthreads();  // tile-0 DMA complete (vmcnt drained)

    float m_run = -1e30f, m_true = -1e30f, l_run = 0.f;
    f32x4 acc[4];
    #pragma unroll
    for (int i = 0; i < 4; ++i) acc[i] = (f32x4){0.f, 0.f, 0.f, 0.f};

    for (int kt = 0; kt <= qt; ++kt) {
      const bool diag = (kt == qt);
      const bool has_next = (kt < qt) || (ph == 0);
      if (has_next) {
        stage(cur ^ 1, diag ? 0 : kt + 1);  // ph0 diag prefetches ph1's tile 0
        __builtin_amdgcn_sched_barrier(0);
      }

      const unsigned char* KL = lds + cur * BUFSZ;
      const unsigned char* VT = KL + KTILE;

      // ---- QK^T swapped: C[k_local][q] = K . Q ----
      const int cbmax = diag ? wv : 3;
      f32x4 sc[4];
      #pragma unroll
      for (int cb = 0; cb < 4; ++cb) sc[cb] = (f32x4){0.f, 0.f, 0.f, 0.f};
      #pragma unroll
      for (int cb = 0; cb < 4; ++cb) {
        if (cb <= cbmax) {
          int rbase = (cb * 16 + c) * 256;
          int sw = (c & 7) << 4;  // (row&7)==(c&7)
          #pragma unroll
          for (int dc = 0; dc < 4; ++dc) {
            int byte = rbase + ((dc * 64 + g * 16) ^ sw);
            bf16x8 kf = *(const bf16x8*)(KL + byte);
            sc[cb] = __builtin_amdgcn_mfma_f32_16x16x32_bf16(kf, qf[dc], sc[cb], 0, 0, 0);
          }
        }
      }

      // ---- mask + online softmax (lane owns q-column c) ----
      float p[4][4];
      float mt = -1e30f;
      if (!diag) {
        #pragma unroll
        for (int cb = 0; cb < 4; ++cb) {
          #pragma unroll
          for (int r = 0; r < 4; ++r) {
            float v = sc[cb][r];
            p[cb][r] = v;
            mt = fmaxf(mt, v);
          }
        }
      } else {
        const int qloc = wv * 16 + c;
        #pragma unroll
        for (int cb = 0; cb < 4; ++cb) {
          #pragma unroll
          for (int r = 0; r < 4; ++r) {
            int kloc = cb * 16 + g * 4 + r;
            float v = (cb <= cbmax && kloc <= qloc) ? sc[cb][r] : -1e30f;
            p[cb][r] = v;
            mt = fmaxf(mt, v);
          }
        }
      }
      mt = fmaxf(mt, __shfl_xor(mt, 16));
      mt = fmaxf(mt, __shfl_xor(mt, 32));
      m_true = fmaxf(m_true, mt);

      float resc = 1.0f;
      if (!__all(mt <= m_run + 8.0f)) {  // T13 defer-max
        float m_new = fmaxf(m_run, mt);
        resc = __expf(m_run - m_new);
        m_run = m_new;
        #pragma unroll
        for (int r = 0; r < 4; ++r) {
          float f = __shfl(resc, g * 4 + r);
          #pragma unroll
          for (int db = 0; db < 4; ++db) acc[db][r] *= f;
        }
      }
      float ls = 0.f;
      #pragma unroll
      for (int cb = 0; cb < 4; ++cb) {
        #pragma unroll
        for (int r = 0; r < 4; ++r) {
          float e = __expf(p[cb][r] - m_run);
          p[cb][r] = e;
          ls += e;
        }
      }
      ls += __shfl_xor(ls, 16);
      ls += __shfl_xor(ls, 32);
      l_run = l_run * resc + ls;

      // ---- redistribute P into A-operand fragments (verified shfl form) ----
      unsigned pk2[4][2];
      #pragma unroll
      for (int cb = 0; cb < 4; ++cb) {
        pk2[cb][0] = pkbf(p[cb][0], p[cb][1]);
        pk2[cb][1] = pkbf(p[cb][2], p[cb][3]);
      }
      const int srcA = c + 16 * ((2 * g) & 3);
      const int srcB = c + 16 * ((2 * g + 1) & 3);
      const bool hi = (g & 2) != 0;
      const int sbmax = diag ? (wv >> 1) : 1;
      #pragma unroll
      for (int sb = 0; sb < 2; ++sb) {
        if (sb <= sbmax) {
          unsigned a0 = (unsigned)__shfl((int)pk2[2 * sb][0], srcA);
          unsigned b0 = (unsigned)__shfl((int)pk2[2 * sb + 1][0], srcA);
          unsigned a1 = (unsigned)__shfl((int)pk2[2 * sb][1], srcA);
          unsigned b1 = (unsigned)__shfl((int)pk2[2 * sb + 1][1], srcA);
          unsigned a2 = (unsigned)__shfl((int)pk2[2 * sb][0], srcB);
          unsigned b2 = (unsigned)__shfl((int)pk2[2 * sb + 1][0], srcB);
          unsigned a3 = (unsigned)__shfl((int)pk2[2 * sb][1], srcB);
          unsigned b3 = (unsigned)__shfl((int)pk2[2 * sb + 1][1], srcB);
          U8 pa;
          pa.u[0] = hi ? b0 : a0;
          pa.u[1] = hi ? b1 : a1;
          pa.u[2] = hi ? b2 : a2;
          pa.u[3] = hi ? b3 : a3;
          // ---- PV: acc[db] += P[16q x 32s] * V[32s x 16d] ----
          #pragma unroll
          for (int db = 0; db < 4; ++db) {
            int row = db * 16 + c;
            int byte = row * 128 + (((sb * 32 + g * 8) * 2) ^ ((row & 7) << 4));
            U8 vbf;
            *(uint4*)vbf.u = *(const uint4*)(VT + byte);
            acc[db] = __builtin_amdgcn_mfma_f32_16x16x32_bf16(pa.v, vbf.v, acc[db], 0, 0, 0);
          }
        }
      }

      if (has_next) __syncthreads();  // drains DMA vmcnt + protects buffers
      cur ^= 1;
    }

    // ---- epilogue: normalize, scatter ctx (this d-half), write denom ----
    float inv = 1.0f / l_run;
    #pragma unroll
    for (int r = 0; r < 4; ++r) {
      float fi = __shfl(inv, g * 4 + r);
      int q2 = qbase + g * 4 + r;
      float* orow = Og + (size_t)(q2 * DEG + hm4) * TOKS + bhoff + dbase;
      #pragma unroll
      for (int db = 0; db < 4; ++db) orow[db * 16 + c] = acc[db][r] * fi;
    }
    if (g == 0 && dhv == 0)
      Dg[(size_t)(qbase + c) * (NB * NH) + b * NH + h] =
          l_run * __expf(m_run - m_true);
  }
}

extern "C" void kernel_launch(void* const* d_in, const int* in_sizes, int n_in,
                              void* d_out, int out_size, void* d_ws, size_t ws_size,
                              hipStream_t stream) {
  (void)in_sizes; (void)n_in; (void)out_size; (void)ws_size;
  const float* q = (const float*)d_in[0];
  const float* k = (const float*)d_in[1];
  const float* v = (const float*)d_in[2];
  float* out = (float*)d_out;
  float* den = out + (size_t)S_TOK * NB * NH * DH;
  unsigned char* Kb = (unsigned char*)d_ws;
  unsigned char* Vb = Kb + KB_BYTES;
  mlsa_conv<<<dim3(3072), dim3(256), 0, stream>>>(k, v, Kb, Vb);
  mlsa_attn<<<dim3(512), dim3(256), 0, stream>>>(q, Kb, Vb, out, den);
}